// Round 6
// baseline (301.776 us; speedup 1.0000x reference)
//
#include <hip/hip_runtime.h>
#include <hip/hip_bf16.h>
#include <stdint.h>

#define NODES 50000
#define EDGES 800000

// ---- counting-sort geometry ----
#define EPB 4096                                    // edges per sort block
#define NBLK ((EDGES + EPB - 1) / EPB)              // 196
#define NBUK ((NODES + 63) / 64)                    // 782 coarse buckets (dst>>6)
#define NBUKP 1024                                  // padded (1 bucket / thread @1024)
#define CAP 2560                                    // per-bucket record cap (mean 1023)

#define NTILE (NODES / 16)                          // 3125 row tiles

typedef short bf16x8 __attribute__((ext_vector_type(8)));
typedef float f32x4 __attribute__((ext_vector_type(4)));

__device__ __forceinline__ unsigned short f2bf(float f) {
    union { float f; unsigned u; } v; v.f = f;
    unsigned r = v.u + 0x7fff + ((v.u >> 16) & 1);   // RNE
    return (unsigned short)(r >> 16);
}
__device__ __forceinline__ float bf2f(unsigned short h) {
    union { float f; unsigned u; } v; v.u = ((unsigned)h) << 16;
    return v.f;
}
__device__ __forceinline__ float bflo(unsigned hv) {
    union { float f; unsigned u; } v; v.u = hv << 16;
    return v.f;
}
__device__ __forceinline__ float bfhi(unsigned hv) {
    union { float f; unsigned u; } v; v.u = hv & 0xffff0000u;
    return v.f;
}

// ---------------- W pre-swizzle (unchanged) ----------------
__device__ __forceinline__ void wfrag_one(const float* __restrict__ W, unsigned short* Wf,
                                          int idx, int K, int Nn) {
    int NT = Nn >> 4;
    int lane = idx & 63;
    int f = idx >> 6;
    int nt = f % NT;
    int k0 = (f / NT) << 5;
    int n = (nt << 4) + (lane & 15);
    int kk = k0 + ((lane >> 4) << 3);
    unsigned short o[8];
#pragma unroll
    for (int j = 0; j < 8; j++) o[j] = f2bf(W[(kk + j) * Nn + n]);
    ((uint4*)Wf)[idx] = *(uint4*)o;
}

// ---------------- fused: per-block histograms @1024thr || W swizzle ----------
// hist @256thr was the R2-style straggler shape (196 low-TLP blocks); 1024thr
// gives 4x waves. W swizzle rides along (needed before k_hscan_gemm1).
__global__ __launch_bounds__(1024) void
k_hist_wswz(const int* __restrict__ dst, unsigned* __restrict__ hist,
            int* __restrict__ cursor,
            const float* __restrict__ W1, unsigned short* Wf1,
            const float* __restrict__ W2, unsigned short* Wf2,
            const float* __restrict__ W3, unsigned short* Wf3) {
    if ((int)blockIdx.x < NBLK) {
        __shared__ unsigned cnt[NBUK];
        int t = threadIdx.x;
        for (int i = t; i < NBUK; i += 1024) cnt[i] = 0;
        __syncthreads();
        int base = blockIdx.x * EPB;
#pragma unroll
        for (int i = 0; i < EPB / 1024; i++) {
            int e = base + i * 1024 + t;
            if (e < EDGES) atomicAdd(&cnt[((unsigned)dst[e]) >> 6], 1u);
        }
        __syncthreads();
        for (int b = t; b < NBUK; b += 1024) hist[b * NBLK + blockIdx.x] = cnt[b];
    } else {
        int idx = ((int)blockIdx.x - NBLK) * 1024 + threadIdx.x;
        if (idx == 0) *cursor = 0;
        if (idx < 4096) wfrag_one(W1, Wf1, idx, 256, 128);
        else if (idx < 6144) wfrag_one(W2, Wf2, idx - 4096, 128, 128);
        else if (idx < 7168) wfrag_one(W3, Wf3, idx - 6144, 128, 64);
    }
}

// ---------------- GEMM tile body: swapped-operand MFMA -> coalesced C-store --
template <int K, int Nn, bool A_F32>
__device__ __forceinline__ void gemm_tile(const void* __restrict__ A_,
                                          const uint4* __restrict__ Wf,
                                          unsigned short* __restrict__ Hout, int tile) {
    constexpr int NT = Nn / 16;
    int lane = threadIdx.x & 63;
    if (tile * 16 >= NODES) return;
    int row = tile * 16 + (lane & 15);
    int kbase = (lane >> 4) * 8;

    f32x4 acc[NT];
#pragma unroll
    for (int i = 0; i < NT; i++) acc[i] = (f32x4){0.f, 0.f, 0.f, 0.f};

    for (int k0 = 0; k0 < K; k0 += 32) {
        bf16x8 a;
        if (A_F32) {
            const float* A = (const float*)A_;
            const float4* pp = (const float4*)&A[(size_t)row * K + k0 + kbase];
            float4 u0 = pp[0], u1 = pp[1];
            unsigned short t[8];
            t[0] = f2bf(u0.x); t[1] = f2bf(u0.y); t[2] = f2bf(u0.z); t[3] = f2bf(u0.w);
            t[4] = f2bf(u1.x); t[5] = f2bf(u1.y); t[6] = f2bf(u1.z); t[7] = f2bf(u1.w);
            a = *(bf16x8*)t;
        } else {
            const unsigned short* A = (const unsigned short*)A_;
            a = *(const bf16x8*)&A[(size_t)row * K + k0 + kbase];
        }
        int fbase = (k0 >> 5) * NT;
#pragma unroll
        for (int nt = 0; nt < NT; nt++) {
            uint4 braw = Wf[(fbase + nt) * 64 + lane];
            bf16x8 b = *(bf16x8*)&braw;
            acc[nt] = __builtin_amdgcn_mfma_f32_16x16x32_bf16(b, a, acc[nt], 0, 0, 0);
        }
    }
    int xr = lane & 15;
    int wg = lane >> 4;                    // col group (4 cols each)
#pragma unroll
    for (int nt = 0; nt < NT; nt++) {
        uint2 pk;
        pk.x = (unsigned)f2bf(acc[nt][0]) | ((unsigned)f2bf(acc[nt][1]) << 16);
        pk.y = (unsigned)f2bf(acc[nt][2]) | ((unsigned)f2bf(acc[nt][3]) << 16);
        ((uint2*)Hout)[(((size_t)(tile * 16 + xr) * Nn + nt * 16) >> 2) + wg] = pk;
    }
}

// ---------------- fused: hscan (even blocks) || gemm1 (odd blocks) -----------
// Independent dataflow: hscan needs hist; gemm1 needs x+Wf1 (both ready).
// 782 blocks each; gemm1's ~25-30us hides under the scan instead of serial.
__global__ void k_hscan_gemm1(const unsigned* __restrict__ hist, uint2* __restrict__ cbB,
                              int2* __restrict__ brange, int* __restrict__ cursor,
                              const float* __restrict__ x, const uint4* __restrict__ Wf1,
                              unsigned short* __restrict__ h) {
    if (blockIdx.x & 1) {
        gemm_tile<256, 128, true>((const void*)x, Wf1, h,
                                  ((int)blockIdx.x >> 1) * 4 + ((int)threadIdx.x >> 6));
        return;
    }
    __shared__ int sm[256];
    __shared__ int s_base;
    int b = (int)blockIdx.x >> 1, t = threadIdx.x;
    int v = (t < NBLK) ? (int)hist[b * NBLK + t] : 0;
    sm[t] = v;
    __syncthreads();
    for (int off = 1; off < 256; off <<= 1) {
        int x2 = (t >= off) ? sm[t - off] : 0;
        __syncthreads();
        sm[t] += x2;
        __syncthreads();
    }
    int total = sm[255];
    if (t == 0) s_base = atomicAdd(cursor, total);
    __syncthreads();
    if (t < NBLK) {
        uint2 cb; cb.x = (unsigned)v; cb.y = (unsigned)(s_base + sm[t] - v);
        cbB[(size_t)t * NBUKP + b] = cb;
    }
    if (t == 0) { int2 r; r.x = s_base; r.y = total; brange[b] = r; }
}

// ---------------- standalone sort (unchanged from R5) ----------------
__global__ __launch_bounds__(1024) void
k_sort(const int* __restrict__ src, const int* __restrict__ dst,
       const float* __restrict__ w, const uint2* __restrict__ cbB,
       int2* __restrict__ rec) {
    __shared__ unsigned long long rec_lds[EPB];   // 32 KB
    __shared__ unsigned cnt[NBUKP];               // 4 KB
    __shared__ unsigned lst[NBUKP];               // 4 KB
    __shared__ unsigned gb[NBUKP];                // 4 KB
    __shared__ int wsum[16];

    int sb = blockIdx.x;
    int t = threadIdx.x;
    int lane = t & 63;
    int wid = t >> 6;

    uint2 cb = cbB[(size_t)sb * NBUKP + t];
    int v = (t < NBUK) ? (int)cb.x : 0;
    gb[t] = (t < NBUK) ? cb.y : 0u;

    // wave-level inclusive scan of v
    int incl = v;
#pragma unroll
    for (int d = 1; d < 64; d <<= 1) {
        int y = __shfl_up(incl, d, 64);
        if (lane >= d) incl += y;
    }
    if (lane == 63) wsum[wid] = incl;
    __syncthreads();
    if (wid == 0) {
        int s = (lane < 16) ? wsum[lane] : 0;
#pragma unroll
        for (int d = 1; d < 16; d <<= 1) {
            int y = __shfl_up(s, d, 16);
            if ((lane & 15) >= d) s += y;
        }
        if (lane < 16) wsum[lane] = s;
    }
    cnt[t] = 0;
    __syncthreads();
    int wpre = (wid > 0) ? wsum[wid - 1] : 0;
    lst[t] = (unsigned)(wpre + incl - v);   // block-local exclusive prefix
    __syncthreads();

    int base = sb * EPB;
    int nrec = EDGES - base; if (nrec > EPB) nrec = EPB;

    // rank + stage into LDS in bucket order
#pragma unroll
    for (int i = 0; i < EPB / 1024; i++) {
        int e = base + i * 1024 + t;
        if (e < EDGES) {
            unsigned d = (unsigned)dst[e];
            unsigned b = d >> 6;
            unsigned r = atomicAdd(&cnt[b], 1u);
            unsigned meta = (unsigned)src[e] | ((d & 63u) << 16) | (b << 22);
            rec_lds[lst[b] + r] = (unsigned long long)meta |
                                  ((unsigned long long)__float_as_uint(w[e]) << 32);
        }
    }
    __syncthreads();

    // sweep: per-bucket contiguous runs -> global
    for (int i = t; i < nrec; i += 1024) {
        unsigned long long vv = rec_lds[i];
        unsigned meta = (unsigned)vv;
        unsigned b = meta >> 22;
        unsigned gpos = gb[b] + ((unsigned)i - lst[b]);
        int2 rc; rc.x = (int)(meta & 0x3FFFFFu); rc.y = (int)(vv >> 32);
        rec[gpos] = rc;
    }
}

// ---------------- per-bucket node sort + deg/dis/rsc (unchanged) -------------
__global__ void k_sub(int2* __restrict__ rec, const int2* __restrict__ brange,
                      float* __restrict__ dis, int2* __restrict__ rsc) {
    __shared__ int2 stage[CAP];
    __shared__ unsigned short ipos[CAP];
    __shared__ unsigned cnt[64];
    __shared__ unsigned lst[64];
    __shared__ float degw[64];
    int t = threadIdx.x, b = blockIdx.x;
    int2 br = brange[b];
    int base = br.x;
    int n = br.y; if (n > CAP) n = CAP;

    if (t < 64) { cnt[t] = 0; degw[t] = 0.f; }
    __syncthreads();
    for (int i = t; i < n; i += 256) {
        int2 rc = rec[base + i];
        stage[i] = rc;
        unsigned dl = ((unsigned)rc.x >> 16) & 63u;
        atomicAdd(&cnt[dl], 1u);
        atomicAdd(&degw[dl], __int_as_float(rc.y));
    }
    __syncthreads();
    if (t == 0) {
        unsigned run = 0;
        for (int j = 0; j < 64; j++) { lst[j] = run; run += cnt[j]; }
    }
    __syncthreads();
    if (t < 64) {
        int node = b * 64 + t;
        if (node < NODES) {
            dis[node] = rsqrtf(1.0f + degw[t]);            // +1 self-loop
            int2 rs; rs.x = base + (int)lst[t]; rs.y = (int)cnt[t];
            rsc[node] = rs;
        }
    }
    if (t < 64) cnt[t] = 0;
    __syncthreads();
    for (int i = t; i < n; i += 256) {
        unsigned dl = ((unsigned)stage[i].x >> 16) & 63u;
        unsigned r = atomicAdd(&cnt[dl], 1u);
        ipos[lst[dl] + r] = (unsigned short)i;
    }
    __syncthreads();
    for (int i = t; i < n; i += 256) {
        rec[base + i] = stage[ipos[i]];
    }
}

// ---------------- standalone GEMM (layers 2,3) ----------------
template <int K, int Nn, bool A_F32>
__global__ void k_gemm(const void* __restrict__ A_, const uint4* __restrict__ Wf,
                       unsigned short* __restrict__ Hout) {
    gemm_tile<K, Nn, A_F32>(A_, Wf, Hout, blockIdx.x * 4 + (threadIdx.x >> 6));
}

// ---------------- Aggregation: 16 gathers in flight ----------------
// Same proven wave-per-node structure; j-loop widened 8 -> 16 (mean deg 16:
// one iteration instead of two). Pre-commit: flat result => 4.9 TB/s random-
// gather throughput wall confirmed.
template <int F, bool RELU, bool OUT_F32>
__global__ void k_agg(const unsigned short* __restrict__ H, const int2* __restrict__ rec,
                      const int2* __restrict__ rsc, const float* __restrict__ dis,
                      const float* __restrict__ bias, void* __restrict__ out_) {
    constexpr int VPT = F / 64;
    int lane = threadIdx.x & 63;
    int node = blockIdx.x * 4 + (threadIdx.x >> 6);
    if (node >= NODES) return;
    node = __builtin_amdgcn_readfirstlane(node);   // wave-uniform -> SGPR

    const unsigned* H32 = (const unsigned*)H;

    float dn = dis[node];
    float acc0, acc1 = 0.f;
    if (VPT == 2) {
        unsigned hv = H32[node * 64 + lane];
        acc0 = dn * bflo(hv);
        acc1 = dn * bfhi(hv);
    } else {
        acc0 = dn * bf2f(H[node * 64 + lane]);
    }

    int2 rs = rsc[node];
    int beg = rs.x, end = rs.x + rs.y;
    int last = end - 1;
    for (int j = beg; j < end; j += 16) {
        int ss[16]; float nn[16];
#pragma unroll
        for (int q = 0; q < 16; q++) {
            int idx = j + q;
            idx = (idx < last) ? idx : last;           // uniform clamp
            int2 rc = rec[idx];                        // scalar load, broadcast
            ss[q] = rc.x & 0xFFFF;
            nn[q] = (j + q < end) ? __int_as_float(rc.y) : 0.0f;
        }
#pragma unroll
        for (int q = 0; q < 16; q++) nn[q] *= dis[ss[q]];   // broadcast loads
        if (VPT == 2) {
            unsigned hh[16];
#pragma unroll
            for (int q = 0; q < 16; q++) hh[q] = H32[ss[q] * 64 + lane];
#pragma unroll
            for (int q = 0; q < 16; q++) {
                acc0 += nn[q] * bflo(hh[q]);
                acc1 += nn[q] * bfhi(hh[q]);
            }
        } else {
            unsigned short hh[16];
#pragma unroll
            for (int q = 0; q < 16; q++) hh[q] = H[ss[q] * 64 + lane];
#pragma unroll
            for (int q = 0; q < 16; q++) acc0 += nn[q] * bf2f(hh[q]);
        }
    }

    if (OUT_F32) {
        float* out = (float*)out_;
        if (VPT == 2) {
            float x0 = dn * acc0 + bias[lane * 2];
            float x1 = dn * acc1 + bias[lane * 2 + 1];
            if (RELU) { x0 = fmaxf(x0, 0.f); x1 = fmaxf(x1, 0.f); }
            out[(size_t)node * F + lane * 2] = x0;
            out[(size_t)node * F + lane * 2 + 1] = x1;
        } else {
            float x0 = dn * acc0 + bias[lane];
            if (RELU) x0 = fmaxf(x0, 0.f);
            out[(size_t)node * F + lane] = x0;
        }
    } else {
        unsigned short* out = (unsigned short*)out_;
        if (VPT == 2) {
            float x0 = dn * acc0 + bias[lane * 2];
            float x1 = dn * acc1 + bias[lane * 2 + 1];
            if (RELU) { x0 = fmaxf(x0, 0.f); x1 = fmaxf(x1, 0.f); }
            unsigned pk = (unsigned)f2bf(x0) | ((unsigned)f2bf(x1) << 16);
            *(unsigned*)&out[(size_t)node * F + lane * 2] = pk;
        } else {
            float x0 = dn * acc0 + bias[lane];
            if (RELU) x0 = fmaxf(x0, 0.f);
            out[(size_t)node * F + lane] = f2bf(x0);
        }
    }
}

// ---------------- launch ----------------

extern "C" void kernel_launch(void* const* d_in, const int* in_sizes, int n_in,
                              void* d_out, int out_size, void* d_ws, size_t ws_size,
                              hipStream_t stream) {
    const float* x  = (const float*)d_in[0];
    const int*   ei = (const int*)d_in[1];
    const float* w  = (const float*)d_in[2];
    const float* W1 = (const float*)d_in[3];
    const float* b1 = (const float*)d_in[4];
    const float* W2 = (const float*)d_in[5];
    const float* b2 = (const float*)d_in[6];
    const float* W3 = (const float*)d_in[7];
    const float* b3 = (const float*)d_in[8];
    const int* src = ei;
    const int* dst = ei + EDGES;

    char* p = (char*)d_ws;
    auto alloc = [&](size_t n) { char* r = p; p += (n + 511) & ~(size_t)511; return r; };
    unsigned*       hist   = (unsigned*)alloc((size_t)NBUK * NBLK * 4);
    uint2*          cbB    = (uint2*)alloc((size_t)NBLK * NBUKP * 8);
    int2*           brange = (int2*)alloc((size_t)NBUK * 8);
    int*            cursor = (int*)alloc(4);
    int2*           rec    = (int2*)alloc((size_t)EDGES * 8);
    float*          dis    = (float*)alloc(NODES * 4);
    int2*           rsc    = (int2*)alloc((size_t)NODES * 8);
    unsigned short* h      = (unsigned short*)alloc((size_t)NODES * 128 * 2);
    unsigned short* xb     = (unsigned short*)alloc((size_t)NODES * 128 * 2);
    unsigned short* wf1    = (unsigned short*)alloc(256 * 128 * 2);
    unsigned short* wf2    = (unsigned short*)alloc(128 * 128 * 2);
    unsigned short* wf3    = (unsigned short*)alloc(128 * 64 * 2);

    const int TB = 256;
    int nb_gemm = (NTILE + 3) / 4;        // 782
    int nb_agg  = (NODES + 3) / 4;        // 12500

    hipLaunchKernelGGL(k_hist_wswz, dim3(NBLK + 7), dim3(1024), 0, stream,
                       dst, hist, cursor, W1, wf1, W2, wf2, W3, wf3);
    hipLaunchKernelGGL(k_hscan_gemm1, dim3(2 * NBUK), dim3(TB), 0, stream,
                       hist, cbB, brange, cursor, x, (const uint4*)wf1, h);
    hipLaunchKernelGGL(k_sort, dim3(NBLK), dim3(1024), 0, stream, src, dst, w, cbB, rec);
    hipLaunchKernelGGL(k_sub, dim3(NBUK), dim3(TB), 0, stream, rec, brange, dis, rsc);

    // Layer 1 aggregation (gemm1 done in the fused hscan launch)
    hipLaunchKernelGGL((k_agg<128, true, false>), dim3(nb_agg), dim3(TB), 0, stream, h, rec, rsc, dis, b1, (void*)xb);

    // Layer 2
    hipLaunchKernelGGL((k_gemm<128, 128, false>), dim3(nb_gemm), dim3(TB), 0, stream, (const void*)xb, (const uint4*)wf2, h);
    hipLaunchKernelGGL((k_agg<128, true, false>), dim3(nb_agg), dim3(TB), 0, stream, h, rec, rsc, dis, b2, (void*)xb);

    // Layer 3 (no relu, fp32 out)
    hipLaunchKernelGGL((k_gemm<128, 64, false>), dim3(nb_gemm), dim3(TB), 0, stream, (const void*)xb, (const uint4*)wf3, h);
    hipLaunchKernelGGL((k_agg<64, false, true>), dim3(nb_agg), dim3(TB), 0, stream, h, rec, rsc, dis, b3, d_out);
}

// Round 7
// 285.535 us; speedup vs baseline: 1.0569x; 1.0569x over previous
//
#include <hip/hip_runtime.h>
#include <hip/hip_bf16.h>
#include <stdint.h>

#define NODES 50000
#define EDGES 800000
#define R_REP 8
#define DEG_EPT 4
#define SCAN_TB 256
#define SCAN_NB ((NODES + SCAN_TB - 1) / SCAN_TB)   // 196
#define NVB_DEG ((EDGES + 1023) / 1024)             // 782
#define NVB_GEMM ((NODES / 16 + 3) / 4)             // 782
#define NTILE (NODES / 16)                          // 3125

typedef short bf16x8 __attribute__((ext_vector_type(8)));
typedef float f32x4 __attribute__((ext_vector_type(4)));

__device__ __forceinline__ unsigned short f2bf(float f) {
    union { float f; unsigned u; } v; v.f = f;
    unsigned r = v.u + 0x7fff + ((v.u >> 16) & 1);   // RNE
    return (unsigned short)(r >> 16);
}
__device__ __forceinline__ float bf2f(unsigned short h) {
    union { float f; unsigned u; } v; v.u = ((unsigned)h) << 16;
    return v.f;
}
__device__ __forceinline__ float bflo(unsigned hv) {
    union { float f; unsigned u; } v; v.u = hv << 16;
    return v.f;
}
__device__ __forceinline__ float bfhi(unsigned hv) {
    union { float f; unsigned u; } v; v.u = hv & 0xffff0000u;
    return v.f;
}

// ---------------- setup: zero replicated counters + cursor + W pre-swizzle ----
// packed[r*NODES+i] (replica-major), u32: bits[31:26]=count, bits[25:0]=weighted
// degree (2^20 fixed point). Self-loop (+1) added at scan. (R1-verified)

__device__ __forceinline__ void wfrag_one(const float* __restrict__ W, unsigned short* Wf,
                                          int idx, int K, int Nn) {
    int NT = Nn >> 4;
    int lane = idx & 63;
    int f = idx >> 6;
    int nt = f % NT;
    int k0 = (f / NT) << 5;
    int n = (nt << 4) + (lane & 15);
    int kk = k0 + ((lane >> 4) << 3);
    unsigned short o[8];
#pragma unroll
    for (int j = 0; j < 8; j++) o[j] = f2bf(W[(kk + j) * Nn + n]);
    ((uint4*)Wf)[idx] = *(uint4*)o;
}

__global__ void k_setup(unsigned* packed, int* cursor,
                        const float* __restrict__ W1, unsigned short* Wf1,
                        const float* __restrict__ W2, unsigned short* Wf2,
                        const float* __restrict__ W3, unsigned short* Wf3) {
    int idx = blockIdx.x * blockDim.x + threadIdx.x;
    if (idx == 0) *cursor = 0;
    if (idx < NODES * R_REP) { packed[idx] = 0u; return; }
    int k = idx - NODES * R_REP;
    if (k < 4096) wfrag_one(W1, Wf1, k, 256, 128);
    else if (k < 6144) wfrag_one(W2, Wf2, k - 4096, 128, 128);
    else if (k < 7168) wfrag_one(W3, Wf3, k - 6144, 128, 64);
}

// ---------------- GEMM tile body: swapped-operand MFMA -> coalesced C-store --
// mfma(b, a, acc): lane&15 = x-row, (lane>>4)*4+r = 4 consecutive w-cols ->
// one uint2 (4 bf16) store per nt (harness-verified R3-R6).
template <int K, int Nn, bool A_F32>
__device__ __forceinline__ void gemm_tile(const void* __restrict__ A_,
                                          const uint4* __restrict__ Wf,
                                          unsigned short* __restrict__ Hout, int tile) {
    constexpr int NT = Nn / 16;
    int lane = threadIdx.x & 63;
    if (tile * 16 >= NODES) return;
    int row = tile * 16 + (lane & 15);
    int kbase = (lane >> 4) * 8;

    f32x4 acc[NT];
#pragma unroll
    for (int i = 0; i < NT; i++) acc[i] = (f32x4){0.f, 0.f, 0.f, 0.f};

    for (int k0 = 0; k0 < K; k0 += 32) {
        bf16x8 a;
        if (A_F32) {
            const float* A = (const float*)A_;
            const float4* pp = (const float4*)&A[(size_t)row * K + k0 + kbase];
            float4 u0 = pp[0], u1 = pp[1];
            unsigned short t[8];
            t[0] = f2bf(u0.x); t[1] = f2bf(u0.y); t[2] = f2bf(u0.z); t[3] = f2bf(u0.w);
            t[4] = f2bf(u1.x); t[5] = f2bf(u1.y); t[6] = f2bf(u1.z); t[7] = f2bf(u1.w);
            a = *(bf16x8*)t;
        } else {
            const unsigned short* A = (const unsigned short*)A_;
            a = *(const bf16x8*)&A[(size_t)row * K + k0 + kbase];
        }
        int fbase = (k0 >> 5) * NT;
#pragma unroll
        for (int nt = 0; nt < NT; nt++) {
            uint4 braw = Wf[(fbase + nt) * 64 + lane];
            bf16x8 b = *(bf16x8*)&braw;
            acc[nt] = __builtin_amdgcn_mfma_f32_16x16x32_bf16(b, a, acc[nt], 0, 0, 0);
        }
    }
    int xr = lane & 15;
    int wg = lane >> 4;                    // col group (4 cols each)
#pragma unroll
    for (int nt = 0; nt < NT; nt++) {
        uint2 pk;
        pk.x = (unsigned)f2bf(acc[nt][0]) | ((unsigned)f2bf(acc[nt][1]) << 16);
        pk.y = (unsigned)f2bf(acc[nt][2]) | ((unsigned)f2bf(acc[nt][3]) << 16);
        ((uint2*)Hout)[(((size_t)(tile * 16 + xr) * Nn + nt * 16) >> 2) + wg] = pk;
    }
}

// ---------------- fused: deg atomics (even blocks) || gemm1 (odd blocks) -----
// R0-measured pattern (50.5us with gemm1 fully hidden under the atomic-RMW
// wall). u32 packed atomic per R1 (same speed, half the zeroing).
__global__ void k_deg_gemm1(const int* __restrict__ dst, const float* __restrict__ w,
                            unsigned* __restrict__ packed, int* __restrict__ rank,
                            const float* __restrict__ x, const uint4* __restrict__ Wf1,
                            unsigned short* __restrict__ h) {
    int half = blockIdx.x >> 1;
    if ((blockIdx.x & 1) == 0) {
        if (half >= NVB_DEG) return;
        int base = half * 1024 + threadIdx.x;
        int r = half & (R_REP - 1);
        unsigned olds[DEG_EPT];
#pragma unroll
        for (int q = 0; q < DEG_EPT; q++) {
            int e = base + q * 256;
            if (e < EDGES) {
                int d = dst[e];
                unsigned add = (1u << 26) | __float2uint_rn(w[e] * 1048576.0f);  // w * 2^20
                olds[q] = atomicAdd(&packed[(size_t)r * NODES + d], add);
            }
        }
#pragma unroll
        for (int q = 0; q < DEG_EPT; q++) {
            int e = base + q * 256;
            if (e < EDGES) rank[e] = (int)(olds[q] >> 26);
        }
    } else {
        if (half >= NVB_GEMM) return;
        gemm_tile<256, 128, true>((const void*)x, Wf1, h, half * 4 + ((int)threadIdx.x >> 6));
    }
}

// ---- scan: reduce replicas -> dis/repoff; block range claimed by one global
// atomicAdd (R1-verified verbatim).
__global__ void k_scan(const unsigned* __restrict__ packed,
                       float* __restrict__ dis, int* __restrict__ repoff,
                       int2* __restrict__ rsc, int* __restrict__ cursor) {
    __shared__ int sm[SCAN_TB];
    __shared__ int s_base;
    int t = threadIdx.x;
    int i = blockIdx.x * SCAN_TB + t;
    int v = 0;
    if (i < NODES) {
        unsigned degfx = 0;
        int off = 0;
#pragma unroll
        for (int r = 0; r < R_REP; r++) {
            unsigned pk = packed[(size_t)r * NODES + i];
            repoff[(size_t)r * NODES + i] = off;   // exclusive prefix over replicas
            off += (int)(pk >> 26);
            degfx += (pk & 0x03FFFFFFu);
        }
        v = off;
        dis[i] = rsqrtf(1.0f + (float)degfx * (1.0f / 1048576.0f));  // +1 self-loop
    }
    sm[t] = v;
    __syncthreads();
    for (int off = 1; off < SCAN_TB; off <<= 1) {
        int x2 = (t >= off) ? sm[t - off] : 0;
        __syncthreads();
        sm[t] += x2;
        __syncthreads();
    }
    int incl = sm[t];
    if (t == SCAN_TB - 1) s_base = atomicAdd(cursor, incl);   // claim range
    __syncthreads();
    if (i < NODES) { int2 rs; rs.x = s_base + incl - v; rs.y = v; rsc[i] = rs; }
}

// atomic-free scatter: pos = rsc[d].start + replica offset + rank.
// r must match k_deg's 1024-edge chunk mapping: r = (e>>10)&7. (R1-verified)
__global__ void k_scatter(const int* __restrict__ src, const int* __restrict__ dst,
                          const float* __restrict__ w, const float* __restrict__ dis,
                          const int2* __restrict__ rsc, const int* __restrict__ repoff,
                          const int* __restrict__ rank, int2* __restrict__ rec) {
    int e = blockIdx.x * blockDim.x + threadIdx.x;
    if (e < EDGES) {
        int r = (e >> 10) & (R_REP - 1);
        int s = src[e], d = dst[e];
        float nrm = dis[s] * w[e] * dis[d];
        int pos = rsc[d].x + repoff[(size_t)r * NODES + d] + rank[e];
        int2 rc; rc.x = s; rc.y = __float_as_int(nrm);
        rec[pos] = rc;
    }
}

// ---------------- standalone GEMM (layers 2,3) ----------------
template <int K, int Nn, bool A_F32>
__global__ void k_gemm(const void* __restrict__ A_, const uint4* __restrict__ Wf,
                       unsigned short* __restrict__ Hout) {
    gemm_tile<K, Nn, A_F32>(A_, Wf, Hout, blockIdx.x * 4 + ((int)threadIdx.x >> 6));
}

// ---------------- Aggregation (R1-verified verbatim; wall-confirmed 8-wide) --
// One wave per node, records on the scalar path (wave-uniform). 8 gathers in
// flight; tail via uniform clamp + zero norm. rec = (src, nrm premultiplied).
template <int F, bool RELU, bool OUT_F32>
__global__ void k_agg(const unsigned short* __restrict__ H, const int2* __restrict__ rec,
                      const int2* __restrict__ rsc, const float* __restrict__ dis,
                      const float* __restrict__ bias, void* __restrict__ out_) {
    constexpr int VPT = F / 64;
    int lane = threadIdx.x & 63;
    int node = blockIdx.x * 4 + (threadIdx.x >> 6);
    if (node >= NODES) return;
    node = __builtin_amdgcn_readfirstlane(node);   // wave-uniform -> SGPR

    const unsigned* H32 = (const unsigned*)H;

    float sn = dis[node]; sn = sn * sn;   // dis^2 = 1/deg (self-loop norm)
    float acc0, acc1 = 0.f;
    if (VPT == 2) {
        unsigned hv = H32[node * 64 + lane];
        acc0 = sn * bflo(hv);
        acc1 = sn * bfhi(hv);
    } else {
        acc0 = sn * bf2f(H[node * 64 + lane]);
    }

    int2 rs = rsc[node];
    int beg = rs.x, end = rs.x + rs.y;
    int last = end - 1;
    for (int j = beg; j < end; j += 8) {
        int ss[8]; float nn[8];
#pragma unroll
        for (int q = 0; q < 8; q++) {
            int idx = j + q;
            idx = (idx < last) ? idx : last;           // uniform clamp
            int2 rc = rec[idx];                        // scalar load, broadcast
            ss[q] = rc.x;
            nn[q] = (j + q < end) ? __int_as_float(rc.y) : 0.0f;
        }
        if (VPT == 2) {
            unsigned hh[8];
#pragma unroll
            for (int q = 0; q < 8; q++) hh[q] = H32[ss[q] * 64 + lane];
#pragma unroll
            for (int q = 0; q < 8; q++) {
                acc0 += nn[q] * bflo(hh[q]);
                acc1 += nn[q] * bfhi(hh[q]);
            }
        } else {
            unsigned short hh[8];
#pragma unroll
            for (int q = 0; q < 8; q++) hh[q] = H[ss[q] * 64 + lane];
#pragma unroll
            for (int q = 0; q < 8; q++) acc0 += nn[q] * bf2f(hh[q]);
        }
    }

    if (OUT_F32) {
        float* out = (float*)out_;
        if (VPT == 2) {
            float x0 = acc0 + bias[lane * 2];
            float x1 = acc1 + bias[lane * 2 + 1];
            if (RELU) { x0 = fmaxf(x0, 0.f); x1 = fmaxf(x1, 0.f); }
            out[(size_t)node * F + lane * 2] = x0;
            out[(size_t)node * F + lane * 2 + 1] = x1;
        } else {
            float x0 = acc0 + bias[lane];
            if (RELU) x0 = fmaxf(x0, 0.f);
            out[(size_t)node * F + lane] = x0;
        }
    } else {
        unsigned short* out = (unsigned short*)out_;
        if (VPT == 2) {
            float x0 = acc0 + bias[lane * 2];
            float x1 = acc1 + bias[lane * 2 + 1];
            if (RELU) { x0 = fmaxf(x0, 0.f); x1 = fmaxf(x1, 0.f); }
            unsigned pk = (unsigned)f2bf(x0) | ((unsigned)f2bf(x1) << 16);
            *(unsigned*)&out[(size_t)node * F + lane * 2] = pk;
        } else {
            float x0 = acc0 + bias[lane];
            if (RELU) x0 = fmaxf(x0, 0.f);
            out[(size_t)node * F + lane] = f2bf(x0);
        }
    }
}

// ---------------- launch ----------------

extern "C" void kernel_launch(void* const* d_in, const int* in_sizes, int n_in,
                              void* d_out, int out_size, void* d_ws, size_t ws_size,
                              hipStream_t stream) {
    const float* x  = (const float*)d_in[0];
    const int*   ei = (const int*)d_in[1];
    const float* w  = (const float*)d_in[2];
    const float* W1 = (const float*)d_in[3];
    const float* b1 = (const float*)d_in[4];
    const float* W2 = (const float*)d_in[5];
    const float* b2 = (const float*)d_in[6];
    const float* W3 = (const float*)d_in[7];
    const float* b3 = (const float*)d_in[8];
    const int* src = ei;
    const int* dst = ei + EDGES;

    char* p = (char*)d_ws;
    auto alloc = [&](size_t n) { char* r = p; p += (n + 511) & ~(size_t)511; return r; };
    unsigned*       packed = (unsigned*)alloc((size_t)NODES * R_REP * 4);
    float*          dis    = (float*)alloc(NODES * 4);
    int2*           rsc    = (int2*)alloc((size_t)NODES * 8);
    int*            repoff = (int*)alloc((size_t)NODES * R_REP * 4);
    int*            rank   = (int*)alloc(EDGES * 4);
    int*            cursor = (int*)alloc(4);
    int2*           rec    = (int2*)alloc((size_t)EDGES * 8);
    unsigned short* h      = (unsigned short*)alloc((size_t)NODES * 128 * 2);
    unsigned short* xb     = (unsigned short*)alloc((size_t)NODES * 128 * 2);
    unsigned short* wf1    = (unsigned short*)alloc(256 * 128 * 2);
    unsigned short* wf2    = (unsigned short*)alloc(128 * 128 * 2);
    unsigned short* wf3    = (unsigned short*)alloc(128 * 64 * 2);

    const int TB = 256;
    int nb_setup = (NODES * R_REP + 7168 + TB - 1) / TB;
    int nb_fused = 2 * ((NVB_DEG > NVB_GEMM) ? NVB_DEG : NVB_GEMM);   // 1564
    int nb_edges = (EDGES + TB - 1) / TB;
    int nb_gemm  = (NTILE + 3) / 4;       // 782
    int nb_agg   = (NODES + 3) / 4;       // 12500

    hipLaunchKernelGGL(k_setup, dim3(nb_setup), dim3(TB), 0, stream,
                       packed, cursor, W1, wf1, W2, wf2, W3, wf3);
    hipLaunchKernelGGL(k_deg_gemm1, dim3(nb_fused), dim3(TB), 0, stream,
                       dst, w, packed, rank, x, (const uint4*)wf1, h);
    hipLaunchKernelGGL(k_scan, dim3(SCAN_NB), dim3(SCAN_TB), 0, stream,
                       packed, dis, repoff, rsc, cursor);
    hipLaunchKernelGGL(k_scatter, dim3(nb_edges), dim3(TB), 0, stream,
                       src, dst, w, dis, rsc, repoff, rank, rec);

    // Layer 1 aggregation (gemm1 done in the fused launch)
    hipLaunchKernelGGL((k_agg<128, true, false>), dim3(nb_agg), dim3(TB), 0, stream, h, rec, rsc, dis, b1, (void*)xb);

    // Layer 2
    hipLaunchKernelGGL((k_gemm<128, 128, false>), dim3(nb_gemm), dim3(TB), 0, stream, (const void*)xb, (const uint4*)wf2, h);
    hipLaunchKernelGGL((k_agg<128, true, false>), dim3(nb_agg), dim3(TB), 0, stream, h, rec, rsc, dis, b2, (void*)xb);

    // Layer 3 (no relu, fp32 out)
    hipLaunchKernelGGL((k_gemm<128, 64, false>), dim3(nb_gemm), dim3(TB), 0, stream, (const void*)xb, (const uint4*)wf3, h);
    hipLaunchKernelGGL((k_agg<64, false, true>), dim3(nb_agg), dim3(TB), 0, stream, h, rec, rsc, dis, b3, d_out);
}